// Round 6
// baseline (65.207 us; speedup 1.0000x reference)
//
#include <hip/hip_runtime.h>

#define Bn 8
#define Sn 8192
#define Dn 128
#define NCn 128

typedef _Float16 f16;
typedef f16 f16x2 __attribute__((ext_vector_type(2)));
typedef f16 f16x4 __attribute__((ext_vector_type(4)));
typedef float f32x4 __attribute__((ext_vector_type(4)));

static __device__ __forceinline__ f32x4 mfma16(f16x4 a, f16x4 b, f32x4 c) {
  return __builtin_amdgcn_mfma_f32_16x16x16f16(a, b, c, 0, 0, 0);
}

union UU { uint4 u; f16x2 h[4]; };

// Validated fragment conventions for mfma_f32_16x16x16f16 (rounds 0,2,3,4):
//   A-frag: lane l, reg j = A_op[l&15][4*(l>>4)+j]
//   B-frag: lane l, reg j = B_op[4*(l>>4)+j][l&15]
//   D-frag: lane l, reg j = D[4*(l>>4)+j][l&15]
//   D-frag of u == A-frag of u^T (in-register); packed D-frag [(r*8+c)*64+lane]
//   == B-frag for row-contraction (validated rounds 3-4).

// dst[c*136 + r] = (f16)src[r][c]  (transpose, pitch 136)
static __device__ __forceinline__ void stage_T136(const float* __restrict__ src,
                                                  f16* __restrict__ dst, int tid) {
#pragma unroll
  for (int ii = 0; ii < 4; ++ii) {
    int id = ii * 256 + tid;
    int r4 = id >> 5, c4 = id & 31;
    float4 row[4];
#pragma unroll
    for (int i = 0; i < 4; ++i)
      row[i] = *(const float4*)(src + (r4 * 4 + i) * 128 + c4 * 4);
#pragma unroll
    for (int j = 0; j < 4; ++j) {
      f16x4 col = {(f16)(((const float*)&row[0])[j]), (f16)(((const float*)&row[1])[j]),
                   (f16)(((const float*)&row[2])[j]), (f16)(((const float*)&row[3])[j])};
      *(f16x4*)&dst[(c4 * 4 + j) * 136 + r4 * 4] = col;
    }
  }
}

// ---- precompute, slab-parallel (8 blocks): blocks 0-3: Amat = Wq^T Wk slabs;
// blocks 4-7: r2 = Wout Wv slabs. Row-major f16 [128][128] outputs. ----
__global__ __launch_bounds__(256) void k_prep(
    const float* __restrict__ Wq, const float* __restrict__ Wk,
    const float* __restrict__ Wv, const float* __restrict__ Wout,
    f16* __restrict__ Amat, f16* __restrict__ r2) {
  __shared__ __align__(16) f16 Ls[32 * 136];
  __shared__ __align__(16) f16 R[128 * 136];
  const int blk = blockIdx.x;
  const int which = blk >> 2, j = blk & 3;
  const int tid = threadIdx.x;
  if (which == 0) {
    // L_slab[r][k] = Wq^T[32j+r][k] = Wq[k][32j+r]; R = Wk^T
    int kb = tid >> 3, cb = tid & 7;
    float4 row[4];
#pragma unroll
    for (int i = 0; i < 4; ++i)
      row[i] = *(const float4*)(Wq + (kb * 4 + i) * 128 + j * 32 + cb * 4);
#pragma unroll
    for (int jj = 0; jj < 4; ++jj) {
      f16x4 col = {(f16)(((const float*)&row[0])[jj]), (f16)(((const float*)&row[1])[jj]),
                   (f16)(((const float*)&row[2])[jj]), (f16)(((const float*)&row[3])[jj])};
      *(f16x4*)&Ls[(cb * 4 + jj) * 136 + kb * 4] = col;
    }
    stage_T136(Wk, R, tid);
  } else {
    // L_slab[r][k] = Wout[32j+r][k]; R = Wv^T
    int r = tid >> 3, sub = tid & 7;
#pragma unroll
    for (int i = 0; i < 4; ++i) {
      int col = sub * 4 + i * 32;
      float4 v = *(const float4*)(Wout + (j * 32 + r) * 128 + col);
      f16x4 h = {(f16)v.x, (f16)v.y, (f16)v.z, (f16)v.w};
      *(f16x4*)&Ls[r * 136 + col] = h;
    }
    stage_T136(Wv, R, tid);
  }
  __syncthreads();
  const int w = tid >> 6, lane = tid & 63, r16 = lane & 15, g4 = lane >> 4;
  const int rt = w & 1, cb4 = (w >> 1) * 4;
  f32x4 acc[4] = {};
#pragma unroll
  for (int kk = 0; kk < 8; ++kk) {
    f16x4 af = *(f16x4*)&Ls[(rt * 16 + r16) * 136 + kk * 16 + g4 * 4];
#pragma unroll
    for (int t = 0; t < 4; ++t) {
      f16x4 bf = *(f16x4*)&R[((cb4 + t) * 16 + r16) * 136 + kk * 16 + g4 * 4];
      acc[t] = mfma16(af, bf, acc[t]);
    }
  }
  f16* dst = which ? r2 : Amat;
#pragma unroll
  for (int t = 0; t < 4; ++t)
#pragma unroll
    for (int jj = 0; jj < 4; ++jj)
      dst[(j * 32 + rt * 16 + g4 * 4 + jj) * 128 + (cb4 + t) * 16 + r16] = (f16)acc[t][jj];
}

// ---- fused: gate, u = x Amat^T, v = x r2^T, Z = (g.u)^T v, packed-frag output ----
// XCD-grouped remap (same as k_out) so Z lands on the L2 that re-reads it.
__global__ __launch_bounds__(512, 4) void k_phase1(
    const float* __restrict__ x, const float* __restrict__ gw, const float* __restrict__ gb,
    const f16* __restrict__ Amat, const f16* __restrict__ r2,
    f16x4* __restrict__ wtg, float* __restrict__ gavg) {
  __shared__ __align__(16) f16 Xs[64][136];
  __shared__ __align__(16) f16x4 vP[4096];
  __shared__ float gs[64];
  const int h = blockIdx.x;
  const int grp = h & 127, m = h >> 7;
  const int b = grp >> 4, seg = grp & 15;
  const int c = seg * 8 + m;
  const int tid = threadIdx.x;
  {
    int s = tid >> 3, sub = tid & 7;
    const float* xrow = x + ((size_t)b * Sn + (size_t)c * 64 + s) * Dn;
    float gpart = 0.f;
#pragma unroll
    for (int i = 0; i < 4; ++i) {
      int col = sub * 4 + i * 32;
      float4 v = *(const float4*)(xrow + col);
      float4 g = *(const float4*)(gw + col);
      gpart += v.x * g.x + v.y * g.y + v.z * g.z + v.w * g.w;
      f16x4 hh = {(f16)v.x, (f16)v.y, (f16)v.z, (f16)v.w};
      *(f16x4*)&Xs[s][col] = hh;
    }
    gpart += __shfl_xor(gpart, 1);
    gpart += __shfl_xor(gpart, 2);
    gpart += __shfl_xor(gpart, 4);
    if (sub == 0) gs[s] = 1.f / (1.f + __expf(-(gpart + gb[0])));
  }
  __syncthreads();
  if (tid == 0) {
    float sum = 0.f;
#pragma unroll
    for (int i = 0; i < 64; ++i) sum += gs[i];
    gavg[b * NCn + c] = sum * (1.f / 64.f);
  }
  const int w = tid >> 6, lane = tid & 63, r16 = lane & 15, g4 = lane >> 4;

  f32x4 uacc[4] = {}, vacc[4] = {};
#pragma unroll
  for (int kk = 0; kk < 8; ++kk) {
    f16x4 bu = *(const f16x4*)&Amat[(w * 16 + r16) * 128 + kk * 16 + g4 * 4];
    f16x4 bv = *(const f16x4*)&r2[(w * 16 + r16) * 128 + kk * 16 + g4 * 4];
#pragma unroll
    for (int mr = 0; mr < 4; ++mr) {
      f16x4 af = *(f16x4*)&Xs[mr * 16 + r16][kk * 16 + g4 * 4];
      uacc[mr] = mfma16(af, bu, uacc[mr]);
      vacc[mr] = mfma16(af, bv, vacc[mr]);
    }
  }
  f16x4 ua[4];
#pragma unroll
  for (int mr = 0; mr < 4; ++mr) {
    float g0 = gs[mr * 16 + g4 * 4 + 0], g1 = gs[mr * 16 + g4 * 4 + 1];
    float g2 = gs[mr * 16 + g4 * 4 + 2], g3 = gs[mr * 16 + g4 * 4 + 3];
    f16x4 uh = {(f16)(uacc[mr][0] * g0), (f16)(uacc[mr][1] * g1),
                (f16)(uacc[mr][2] * g2), (f16)(uacc[mr][3] * g3)};
    ua[mr] = uh;
    f16x4 vh = {(f16)vacc[mr][0], (f16)vacc[mr][1], (f16)vacc[mr][2], (f16)vacc[mr][3]};
    vP[(mr * 8 + w) * 64 + lane] = vh;
  }
  __syncthreads();

  f32x4 z[8] = {};
#pragma unroll
  for (int ks = 0; ks < 4; ++ks)
#pragma unroll
    for (int ct = 0; ct < 8; ++ct)
      z[ct] = mfma16(ua[ks], vP[(ks * 8 + ct) * 64 + lane], z[ct]);

  f16x4* wdst = wtg + (size_t)(b * NCn + c) * 4096;
#pragma unroll
  for (int ct = 0; ct < 8; ++ct) {
    f16x4 zh = {(f16)z[ct][0], (f16)z[ct][1], (f16)z[ct][2], (f16)z[ct][3]};
    wdst[(w * 8 + ct) * 64 + lane] = zh;
  }
}

// ---- scan: read all Z, write ONLY segment-boundary carries P_s (inclusive
// prefix through chunk 8s-1), s = 1..15 stored at index s-1. f16 packed. ----
__global__ __launch_bounds__(256) void k_scan(
    const uint* __restrict__ wtg, const float* __restrict__ gavg, uint* __restrict__ pbuf) {
  const int blk = blockIdx.x;
  const int b = blk >> 5;
  const int e = (blk & 31) * 256 + threadIdx.x;
  const uint* wp = wtg + (size_t)b * (NCn * 8192) + e;
  uint* pp = pbuf + (size_t)b * (15 * 8192) + e;
  const float* ga = gavg + b * NCn;
  float M0 = 0.f, M1 = 0.f;
  uint ubuf[16];
  float abuf[16];
#pragma unroll
  for (int i = 0; i < 16; ++i) {
    ubuf[i] = wp[(size_t)i * 8192];
    abuf[i] = ga[i];
  }
  for (int g = 0; g < 8; ++g) {
    uint un[16];
    float an[16];
    if (g < 7) {
#pragma unroll
      for (int i = 0; i < 16; ++i) {
        un[i] = wp[(size_t)((g + 1) * 16 + i) * 8192];
        an[i] = ga[(g + 1) * 16 + i];
      }
    }
#pragma unroll
    for (int i = 0; i < 16; ++i) {
      int cc = g * 16 + i;
      f16x2 wv = __builtin_bit_cast(f16x2, ubuf[i]);
      float dd = 1.f - abuf[i];
      M0 = dd * M0 + (float)wv[0];
      M1 = dd * M1 + (float)wv[1];
      if ((cc & 7) == 7 && cc < 120) {
        f16x2 mv = {(f16)M0, (f16)M1};
        pp[(size_t)(cc >> 3) * 8192] = __builtin_bit_cast(uint, mv);
      }
    }
    if (g < 7) {
#pragma unroll
      for (int i = 0; i < 16; ++i) { ubuf[i] = un[i]; abuf[i] = an[i]; }
    }
  }
}

// ---- out_c = x_c Zhat_{c-1}, Zhat reconstructed: sum_t sfac_t Z_{base+t} + sP P_{seg-1} ----
__global__ __launch_bounds__(512, 4) void k_out(
    const float* __restrict__ x, const uint4* __restrict__ wtg4,
    const uint4* __restrict__ pbuf4, const float* __restrict__ gavg,
    float* __restrict__ outp) {
  __shared__ __align__(16) f16 Xs[64][136];
  __shared__ __align__(16) f16x4 zP[4096];
  const int h = blockIdx.x;
  const int grp = h & 127, m = h >> 7;   // 8 blocks of a (b,seg) share h%8 -> same XCD
  const int b = grp >> 4, seg = grp & 15;
  const int c = seg * 8 + m;
  const int tid = threadIdx.x;
  {
    int s = tid >> 3, sub = tid & 7;
    const float* xrow = x + ((size_t)b * Sn + (size_t)c * 64 + s) * Dn;
#pragma unroll
    for (int i = 0; i < 4; ++i) {
      int col = sub * 4 + i * 32;
      float4 v = *(const float4*)(xrow + col);
      f16x4 hh = {(f16)v.x, (f16)v.y, (f16)v.z, (f16)v.w};
      *(f16x4*)&Xs[s][col] = hh;
    }
  }
  // decay scalars (uniform per block; static indexing only)
  float d[8], sfac[8];
#pragma unroll
  for (int t = 0; t < 8; ++t)
    d[t] = (t < m) ? (1.f - gavg[b * NCn + seg * 8 + t]) : 1.f;
  sfac[7] = 1.f;
#pragma unroll
  for (int t = 6; t >= 0; --t) sfac[t] = sfac[t + 1] * d[t + 1];
  const float sP = sfac[0] * d[0];

  const uint4* Zp[8];
#pragma unroll
  for (int t = 0; t < 8; ++t)
    Zp[t] = wtg4 + (size_t)(b * NCn + seg * 8 + t) * 2048;  // 2048 uint4 = 32 KB per matrix
  const uint4* Pp = pbuf4 + (size_t)(b * 15 + (seg > 0 ? seg - 1 : 0)) * 2048;

#pragma unroll
  for (int i = 0; i < 4; ++i) {
    int idx = tid + i * 512;  // 0..2047 uint4 = 16384 f16
    float a8[8] = {0.f, 0.f, 0.f, 0.f, 0.f, 0.f, 0.f, 0.f};
    if (seg > 0) {
      UU z; z.u = Pp[idx];
#pragma unroll
      for (int q = 0; q < 4; ++q) {
        a8[2 * q] += sP * (float)z.h[q][0];
        a8[2 * q + 1] += sP * (float)z.h[q][1];
      }
    }
#pragma unroll
    for (int t = 0; t < 8; ++t)
      if (t < m) {
        UU z; z.u = Zp[t][idx];
#pragma unroll
        for (int q = 0; q < 4; ++q) {
          a8[2 * q] += sfac[t] * (float)z.h[q][0];
          a8[2 * q + 1] += sfac[t] * (float)z.h[q][1];
        }
      }
    UU o;
#pragma unroll
    for (int q = 0; q < 4; ++q)
      o.h[q] = (f16x2){(f16)a8[2 * q], (f16)a8[2 * q + 1]};
    ((uint4*)zP)[idx] = o.u;
  }
  __syncthreads();
  const int w = tid >> 6, lane = tid & 63, r16 = lane & 15, g4 = lane >> 4;
  const int mr = w & 3, cb = (w >> 2) * 4;
  f32x4 acc[4] = {};
#pragma unroll
  for (int kk = 0; kk < 8; ++kk) {
    f16x4 af = *(f16x4*)&Xs[mr * 16 + r16][kk * 16 + g4 * 4];
#pragma unroll
    for (int t = 0; t < 4; ++t)
      acc[t] = mfma16(af, zP[(kk * 8 + cb + t) * 64 + lane], acc[t]);
  }
  float* obase = outp + ((size_t)b * Sn + (size_t)c * 64 + mr * 16 + g4 * 4) * Dn;
#pragma unroll
  for (int t = 0; t < 4; ++t)
#pragma unroll
    for (int j = 0; j < 4; ++j)
      obase[(size_t)j * Dn + (cb + t) * 16 + r16] = acc[t][j];
}

extern "C" void kernel_launch(void* const* d_in, const int* in_sizes, int n_in,
                              void* d_out, int out_size, void* d_ws, size_t ws_size,
                              hipStream_t stream) {
  const float* x = (const float*)d_in[0];
  const float* Wq = (const float*)d_in[1];
  const float* Wk = (const float*)d_in[2];
  const float* Wv = (const float*)d_in[3];
  const float* gw = (const float*)d_in[4];
  const float* gb = (const float*)d_in[5];
  const float* Wout = (const float*)d_in[6];

  char* ws = (char*)d_ws;
  f16* Amat = (f16*)(ws + 0);                    // 32 KB
  f16* r2 = (f16*)(ws + 32768);                  // 32 KB
  float* gavg = (float*)(ws + 65536);            // 4 KB
  f16* wtg = (f16*)(ws + 69632);                 // 33.5 MB (Z, packed frags)
  f16* pbuf = (f16*)(ws + 69632 + 33554432);     // 3.84 MB (segment carries)

  k_prep<<<dim3(8), dim3(256), 0, stream>>>(Wq, Wk, Wv, Wout, Amat, r2);
  k_phase1<<<dim3(Bn * NCn), dim3(512), 0, stream>>>(x, gw, gb, Amat, r2, (f16x4*)wtg, gavg);
  k_scan<<<dim3(256), dim3(256), 0, stream>>>((const uint*)wtg, gavg, (uint*)pbuf);
  k_out<<<dim3(Bn * NCn), dim3(512), 0, stream>>>(x, (const uint4*)wtg, (const uint4*)pbuf,
                                                  gavg, (float*)d_out);
}

// Round 7
// 64.292 us; speedup vs baseline: 1.0142x; 1.0142x over previous
//
#include <hip/hip_runtime.h>

#define Bn 8
#define Sn 8192
#define Dn 128
#define NCn 128

typedef _Float16 f16;
typedef f16 f16x2 __attribute__((ext_vector_type(2)));
typedef f16 f16x4 __attribute__((ext_vector_type(4)));
typedef float f32x4 __attribute__((ext_vector_type(4)));

static __device__ __forceinline__ f32x4 mfma16(f16x4 a, f16x4 b, f32x4 c) {
  return __builtin_amdgcn_mfma_f32_16x16x16f16(a, b, c, 0, 0, 0);
}

union UU { uint4 u; f16x2 h[4]; };

// Validated fragment conventions for mfma_f32_16x16x16f16 (rounds 0,2,3,4,6):
//   af from P rows: af[j] = P[rt*16 + (l&15)][kk*16 + 4*(l>>4)+j]
//   bf from Q rows: bf[j] = Q[ct*16 + (l&15)][kk*16 + 4*(l>>4)+j]
//   result R = P.Q^T lands as R[rt*16 + 4*(l>>4)+j][ct*16 + (l&15)]  (D-frag)
//   D-frag of u == A-frag of u^T (in-register); packed D-frag [(r*8+c)*64+lane]
//   == B-frag for row-contraction (validated rounds 3-6).

// ---- precompute: 128 blocks x 1 wave; blocks 0-63: Amat = Wq^T Wk tile (ti,tj);
// blocks 64-127: r2 = Wout Wv tile. Operands straight from global f32. ----
__global__ __launch_bounds__(64) void k_prep(
    const float* __restrict__ Wq, const float* __restrict__ Wk,
    const float* __restrict__ Wv, const float* __restrict__ Wout,
    f16* __restrict__ Amat, f16* __restrict__ r2) {
  const int blk = blockIdx.x;
  const int which = blk >> 6;
  const int t = blk & 63, ti = t >> 3, tj = t & 7;
  const int lane = threadIdx.x & 63, r16 = lane & 15, g4 = lane >> 4;
  f32x4 acc = {};
  if (which == 0) {
    // Amat = Wq^T Wk = P.Q^T, P = Wq^T, Q = Wk^T
#pragma unroll
    for (int kk = 0; kk < 8; ++kk) {
      f16x4 af, bf;
#pragma unroll
      for (int j = 0; j < 4; ++j) {
        af[j] = (f16)Wq[(kk * 16 + g4 * 4 + j) * 128 + ti * 16 + r16];
        bf[j] = (f16)Wk[(kk * 16 + g4 * 4 + j) * 128 + tj * 16 + r16];
      }
      acc = mfma16(af, bf, acc);
    }
  } else {
    // r2 = Wout Wv = P.Q^T, P = Wout (row-major), Q = Wv^T
#pragma unroll
    for (int kk = 0; kk < 8; ++kk) {
      f16x4 af, bf;
      float4 a4 = *(const float4*)(Wout + (ti * 16 + r16) * 128 + kk * 16 + g4 * 4);
      af[0] = (f16)a4.x; af[1] = (f16)a4.y; af[2] = (f16)a4.z; af[3] = (f16)a4.w;
#pragma unroll
      for (int j = 0; j < 4; ++j)
        bf[j] = (f16)Wv[(kk * 16 + g4 * 4 + j) * 128 + tj * 16 + r16];
      acc = mfma16(af, bf, acc);
    }
  }
  f16* dst = which ? r2 : Amat;
#pragma unroll
  for (int j = 0; j < 4; ++j)
    dst[(ti * 16 + g4 * 4 + j) * 128 + tj * 16 + r16] = (f16)acc[j];
}

// ---- fused: gate, u = x Amat^T, v = x r2^T, Z = (g.u)^T v, packed-frag output ----
// LDS 34 KB -> 4 blocks/CU (1024 blocks = single residency generation).
__global__ __launch_bounds__(512, 8) void k_phase1(
    const float* __restrict__ x, const float* __restrict__ gw, const float* __restrict__ gb,
    const f16* __restrict__ Amat, const f16* __restrict__ r2,
    f16x4* __restrict__ wtg, float* __restrict__ gavg) {
  __shared__ __align__(16) f16 Xs[64][136];
  __shared__ __align__(16) f16x4 vP[2048];  // 16 KB: 32 tiles x 64 lanes
  __shared__ float gs[64];
  const int h = blockIdx.x;
  const int grp = h & 127, m = h >> 7;
  const int b = grp >> 4, seg = grp & 15;
  const int c = seg * 8 + m;
  const int tid = threadIdx.x;
  {
    int s = tid >> 3, sub = tid & 7;
    const float* xrow = x + ((size_t)b * Sn + (size_t)c * 64 + s) * Dn;
    float gpart = 0.f;
#pragma unroll
    for (int i = 0; i < 4; ++i) {
      int col = sub * 4 + i * 32;
      float4 v = *(const float4*)(xrow + col);
      float4 g = *(const float4*)(gw + col);
      gpart += v.x * g.x + v.y * g.y + v.z * g.z + v.w * g.w;
      f16x4 hh = {(f16)v.x, (f16)v.y, (f16)v.z, (f16)v.w};
      *(f16x4*)&Xs[s][col] = hh;
    }
    gpart += __shfl_xor(gpart, 1);
    gpart += __shfl_xor(gpart, 2);
    gpart += __shfl_xor(gpart, 4);
    if (sub == 0) gs[s] = 1.f / (1.f + __expf(-(gpart + gb[0])));
  }
  __syncthreads();
  if (tid == 0) {
    float sum = 0.f;
#pragma unroll
    for (int i = 0; i < 64; ++i) sum += gs[i];
    gavg[b * NCn + c] = sum * (1.f / 64.f);
  }
  const int w = tid >> 6, lane = tid & 63, r16 = lane & 15, g4 = lane >> 4;

  f32x4 uacc[4] = {}, vacc[4] = {};
#pragma unroll
  for (int kk = 0; kk < 8; ++kk) {
    f16x4 bu = *(const f16x4*)&Amat[(w * 16 + r16) * 128 + kk * 16 + g4 * 4];
    f16x4 bv = *(const f16x4*)&r2[(w * 16 + r16) * 128 + kk * 16 + g4 * 4];
#pragma unroll
    for (int mr = 0; mr < 4; ++mr) {
      f16x4 af = *(f16x4*)&Xs[mr * 16 + r16][kk * 16 + g4 * 4];
      uacc[mr] = mfma16(af, bu, uacc[mr]);
      vacc[mr] = mfma16(af, bv, vacc[mr]);
    }
  }
  f16x4 ua[4];
#pragma unroll
  for (int mr = 0; mr < 4; ++mr) {
    float g0 = gs[mr * 16 + g4 * 4 + 0], g1 = gs[mr * 16 + g4 * 4 + 1];
    float g2 = gs[mr * 16 + g4 * 4 + 2], g3 = gs[mr * 16 + g4 * 4 + 3];
    f16x4 uh = {(f16)(uacc[mr][0] * g0), (f16)(uacc[mr][1] * g1),
                (f16)(uacc[mr][2] * g2), (f16)(uacc[mr][3] * g3)};
    ua[mr] = uh;
    f16x4 vh = {(f16)vacc[mr][0], (f16)vacc[mr][1], (f16)vacc[mr][2], (f16)vacc[mr][3]};
    vP[(mr * 8 + w) * 64 + lane] = vh;
  }
  __syncthreads();

  f32x4 z[8] = {};
#pragma unroll
  for (int ks = 0; ks < 4; ++ks)
#pragma unroll
    for (int ct = 0; ct < 8; ++ct)
      z[ct] = mfma16(ua[ks], vP[(ks * 8 + ct) * 64 + lane], z[ct]);

  f16x4* wdst = wtg + (size_t)(b * NCn + c) * 4096;
#pragma unroll
  for (int ct = 0; ct < 8; ++ct) {
    f16x4 zh = {(f16)z[ct][0], (f16)z[ct][1], (f16)z[ct][2], (f16)z[ct][3]};
    wdst[(w * 8 + ct) * 64 + lane] = zh;
  }
}

// ---- scan: read all Z, write only segment-boundary carries. 32-deep prefetch. ----
__global__ __launch_bounds__(256) void k_scan(
    const uint* __restrict__ wtg, const float* __restrict__ gavg, uint* __restrict__ pbuf) {
  const int blk = blockIdx.x;
  const int b = blk >> 5;
  const int e = (blk & 31) * 256 + threadIdx.x;
  const uint* wp = wtg + (size_t)b * (NCn * 8192) + e;
  uint* pp = pbuf + (size_t)b * (15 * 8192) + e;
  const float* ga = gavg + b * NCn;
  float M0 = 0.f, M1 = 0.f;
  uint ubuf[32];
  float abuf[32];
#pragma unroll
  for (int i = 0; i < 32; ++i) {
    ubuf[i] = wp[(size_t)i * 8192];
    abuf[i] = ga[i];
  }
  for (int g = 0; g < 4; ++g) {
    uint un[32];
    float an[32];
    if (g < 3) {
#pragma unroll
      for (int i = 0; i < 32; ++i) {
        un[i] = wp[(size_t)((g + 1) * 32 + i) * 8192];
        an[i] = ga[(g + 1) * 32 + i];
      }
    }
#pragma unroll
    for (int i = 0; i < 32; ++i) {
      int cc = g * 32 + i;
      f16x2 wv = __builtin_bit_cast(f16x2, ubuf[i]);
      float dd = 1.f - abuf[i];
      M0 = dd * M0 + (float)wv[0];
      M1 = dd * M1 + (float)wv[1];
      if ((cc & 7) == 7 && cc < 120) {
        f16x2 mv = {(f16)M0, (f16)M1};
        pp[(size_t)(cc >> 3) * 8192] = __builtin_bit_cast(uint, mv);
      }
    }
    if (g < 3) {
#pragma unroll
      for (int i = 0; i < 32; ++i) { ubuf[i] = un[i]; abuf[i] = an[i]; }
    }
  }
}

// ---- out_c = x_c Zhat_{c-1}; Zhat reconstructed in two kk-halves (16 KB zP) ----
__global__ __launch_bounds__(512, 8) void k_out(
    const float* __restrict__ x, const uint4* __restrict__ wtg4,
    const uint4* __restrict__ pbuf4, const float* __restrict__ gavg,
    float* __restrict__ outp) {
  __shared__ __align__(16) f16 Xs[64][136];
  __shared__ __align__(16) f16x4 zP[2048];  // 16 KB: one kk-half of Zhat
  const int h = blockIdx.x;
  const int grp = h & 127, m = h >> 7;  // 8 blocks of a (b,seg) share h%8 -> same XCD
  const int b = grp >> 4, seg = grp & 15;
  const int c = seg * 8 + m;
  const int tid = threadIdx.x;
  {
    int s = tid >> 3, sub = tid & 7;
    const float* xrow = x + ((size_t)b * Sn + (size_t)c * 64 + s) * Dn;
#pragma unroll
    for (int i = 0; i < 4; ++i) {
      int col = sub * 4 + i * 32;
      float4 v = *(const float4*)(xrow + col);
      f16x4 hh = {(f16)v.x, (f16)v.y, (f16)v.z, (f16)v.w};
      *(f16x4*)&Xs[s][col] = hh;
    }
  }
  // decay scalars (uniform per block; static indexing only)
  float d[8], sfac[8];
#pragma unroll
  for (int t = 0; t < 8; ++t)
    d[t] = (t < m) ? (1.f - gavg[b * NCn + seg * 8 + t]) : 1.f;
  sfac[7] = 1.f;
#pragma unroll
  for (int t = 6; t >= 0; --t) sfac[t] = sfac[t + 1] * d[t + 1];
  const float sP = sfac[0] * d[0];

  const uint4* Zbase = wtg4 + (size_t)(b * NCn + seg * 8) * 2048;
  const uint4* Pp = pbuf4 + (size_t)(b * 15 + (seg > 0 ? seg - 1 : 0)) * 2048;

  const int w = tid >> 6, lane = tid & 63, r16 = lane & 15, g4 = lane >> 4;
  const int mr = w & 3, cb = (w >> 2) * 4;
  f32x4 acc[4] = {};

#pragma unroll
  for (int half = 0; half < 2; ++half) {
    if (half) __syncthreads();  // prev half's MFMA reads of zP complete
#pragma unroll
    for (int i = 0; i < 2; ++i) {
      int idx = tid + i * 512;          // 0..1023 uint4 within the half
      int src = half * 1024 + idx;
      float a8[8] = {0.f, 0.f, 0.f, 0.f, 0.f, 0.f, 0.f, 0.f};
      if (seg > 0) {
        UU z; z.u = Pp[src];
#pragma unroll
        for (int q = 0; q < 4; ++q) {
          a8[2 * q] += sP * (float)z.h[q][0];
          a8[2 * q + 1] += sP * (float)z.h[q][1];
        }
      }
#pragma unroll
      for (int t = 0; t < 8; ++t)
        if (t < m) {
          UU z; z.u = Zbase[(size_t)t * 2048 + src];
#pragma unroll
          for (int q = 0; q < 4; ++q) {
            a8[2 * q] += sfac[t] * (float)z.h[q][0];
            a8[2 * q + 1] += sfac[t] * (float)z.h[q][1];
          }
        }
      UU o;
#pragma unroll
      for (int q = 0; q < 4; ++q)
        o.h[q] = (f16x2){(f16)a8[2 * q], (f16)a8[2 * q + 1]};
      ((uint4*)zP)[idx] = o.u;
    }
    __syncthreads();  // zP half ready (also covers Xs staging on half 0)
#pragma unroll
    for (int kk = 0; kk < 4; ++kk) {
      f16x4 af = *(f16x4*)&Xs[mr * 16 + r16][(half * 4 + kk) * 16 + g4 * 4];
#pragma unroll
      for (int t = 0; t < 4; ++t)
        acc[t] = mfma16(af, zP[(kk * 8 + cb + t) * 64 + lane], acc[t]);
    }
  }
  float* obase = outp + ((size_t)b * Sn + (size_t)c * 64 + mr * 16 + g4 * 4) * Dn;
#pragma unroll
  for (int t = 0; t < 4; ++t)
#pragma unroll
    for (int j = 0; j < 4; ++j)
      obase[(size_t)j * Dn + (cb + t) * 16 + r16] = acc[t][j];
}

extern "C" void kernel_launch(void* const* d_in, const int* in_sizes, int n_in,
                              void* d_out, int out_size, void* d_ws, size_t ws_size,
                              hipStream_t stream) {
  const float* x = (const float*)d_in[0];
  const float* Wq = (const float*)d_in[1];
  const float* Wk = (const float*)d_in[2];
  const float* Wv = (const float*)d_in[3];
  const float* gw = (const float*)d_in[4];
  const float* gb = (const float*)d_in[5];
  const float* Wout = (const float*)d_in[6];

  char* ws = (char*)d_ws;
  f16* Amat = (f16*)(ws + 0);                    // 32 KB
  f16* r2 = (f16*)(ws + 32768);                  // 32 KB
  float* gavg = (float*)(ws + 65536);            // 4 KB
  f16* wtg = (f16*)(ws + 69632);                 // 33.5 MB (Z, packed frags)
  f16* pbuf = (f16*)(ws + 69632 + 33554432);     // 3.84 MB (segment carries)

  k_prep<<<dim3(128), dim3(64), 0, stream>>>(Wq, Wk, Wv, Wout, Amat, r2);
  k_phase1<<<dim3(Bn * NCn), dim3(512), 0, stream>>>(x, gw, gb, Amat, r2, (f16x4*)wtg, gavg);
  k_scan<<<dim3(256), dim3(256), 0, stream>>>((const uint*)wtg, gavg, (uint*)pbuf);
  k_out<<<dim3(Bn * NCn), dim3(512), 0, stream>>>(x, (const uint4*)wtg, (const uint4*)pbuf,
                                                  gavg, (float*)d_out);
}